// Round 16
// baseline (2365.950 us; speedup 1.0000x reference)
//
#include <hip/hip_runtime.h>
#include <hip/hip_bf16.h>

#define N_NODES 50000
#define N_EDGES 600000
#define CH 128
#define N_LAYERS 15
#define LAP_BLOCKS 2048

typedef float f32x4 __attribute__((ext_vector_type(4)));
typedef short s16x8 __attribute__((ext_vector_type(8)));

__device__ __forceinline__ float eluf(float v) {
    return v > 0.f ? v : (__expf(v) - 1.f);
}

// float -> bf16 round-to-nearest-even, raw ushort
__device__ __forceinline__ unsigned short f2bf(float f) {
    unsigned int u = __float_as_uint(f);
    unsigned int r = (u + 0x7FFFu + ((u >> 16) & 1u)) >> 16;
    return (unsigned short)r;
}
__device__ __forceinline__ float bf2f(unsigned short h) {
    return __uint_as_float(((unsigned int)h) << 16);
}

// ---------------- conv1: [N,3] @ [3,128] + b ; writes x fp32 + elu planes ----------------
__global__ __launch_bounds__(256) void conv1_kernel(
    const float* __restrict__ in, const float* __restrict__ W1,
    const float* __restrict__ b1, float* __restrict__ x,
    unsigned short* __restrict__ hbh, unsigned short* __restrict__ hbl, int n)
{
    int idx = blockIdx.x * blockDim.x + threadIdx.x;
    if (idx >= n * CH) return;
    int node = idx >> 7;
    int c = idx & 127;
    float o = b1[c]
            + in[(size_t)node * 3 + 0] * W1[0 * CH + c]
            + in[(size_t)node * 3 + 1] * W1[1 * CH + c]
            + in[(size_t)node * 3 + 2] * W1[2 * CH + c];
    x[idx] = o;
    float e = eluf(o);
    unsigned short hi = f2bf(e);
    hbh[idx] = hi;
    hbl[idx] = f2bf(e - bf2f(hi));
}

// ---------------- zero helpers ----------------
__global__ __launch_bounds__(256) void zero_int_kernel(int* __restrict__ p, int n) {
    int i = blockIdx.x * blockDim.x + threadIdx.x;
    if (i < n) p[i] = 0;
}
__global__ __launch_bounds__(256) void zero_float_kernel(float* __restrict__ p, int n) {
    int i = blockIdx.x * blockDim.x + threadIdx.x;
    if (i < n) p[i] = 0.f;
}

// ---------------- CSR build ----------------
__global__ __launch_bounds__(256) void count_kernel(
    const int* __restrict__ row, int* __restrict__ cnt, int e)
{
    int i = blockIdx.x * blockDim.x + threadIdx.x;
    if (i < e) atomicAdd(&cnt[row[i]], 1);
}

__global__ __launch_bounds__(1024) void block_reduce_kernel(
    const int* __restrict__ cnt, int* __restrict__ bsum, int n)
{
    __shared__ int sd[1024];
    int tid = threadIdx.x;
    int i = blockIdx.x * 1024 + tid;
    sd[tid] = (i < n) ? cnt[i] : 0;
    __syncthreads();
    for (int off = 512; off > 0; off >>= 1) {
        if (tid < off) sd[tid] += sd[tid + off];
        __syncthreads();
    }
    if (tid == 0) bsum[blockIdx.x] = sd[0];
}

__global__ __launch_bounds__(64) void scan_small_kernel(
    const int* __restrict__ bsum, int* __restrict__ boff, int nb)
{
    int lane = threadIdx.x;
    int orig = (lane < nb) ? bsum[lane] : 0;
    int v = orig;
#pragma unroll
    for (int d = 1; d < 64; d <<= 1) {
        int t = __shfl_up(v, d, 64);
        if (lane >= d) v += t;
    }
    if (lane < nb) boff[lane] = v - orig;  // exclusive
}

__global__ __launch_bounds__(1024) void block_scan_kernel(
    const int* __restrict__ cnt, const int* __restrict__ boff,
    int* __restrict__ row_ptr, int n)
{
    __shared__ int sd[1024];
    int tid = threadIdx.x;
    int i = blockIdx.x * 1024 + tid;
    sd[tid] = (i < n) ? cnt[i] : 0;
    __syncthreads();
    for (int off = 1; off < 1024; off <<= 1) {
        int t = (tid >= off) ? sd[tid - off] : 0;
        __syncthreads();
        sd[tid] += t;
        __syncthreads();
    }
    if (i < n) row_ptr[i + 1] = sd[tid] + boff[blockIdx.x];
    if (i == 0) row_ptr[0] = 0;
}

// col_s stores byte offset of the gather row start: col * CH * 2 = col << 8
__global__ __launch_bounds__(256) void fill_kernel(
    const int* __restrict__ row, const int* __restrict__ col,
    const float* __restrict__ val, int* __restrict__ cursor,
    const int* __restrict__ row_ptr, int* __restrict__ col_s,
    float* __restrict__ val_s, int e)
{
    int i = blockIdx.x * blockDim.x + threadIdx.x;
    if (i >= e) return;
    int r = row[i];
    int pos = atomicAdd(&cursor[r], 1);
    int dst = row_ptr[r] + pos;
    col_s[dst] = col[i] << 8;
    val_s[dst] = val[i];
}

// ---------------- mask denominator (once per call) ----------------
__global__ __launch_bounds__(256) void mask_sum_kernel(
    const float* __restrict__ mask, float* __restrict__ denom, int n)
{
    __shared__ float sd[256];
    int tid = threadIdx.x;
    float s = 0.f;
    for (int i = blockIdx.x * 256 + tid; i < n; i += gridDim.x * 256) s += mask[i];
    sd[tid] = s;
    __syncthreads();
    for (int off = 128; off > 0; off >>= 1) {
        if (tid < off) sd[tid] += sd[tid + off];
        __syncthreads();
    }
    if (tid == 0) atomicAdd(denom, sd[0]);
}

// ---- W pre-split into MFMA-FRAGMENT-ordered layout:
// Wf[s][plane][chunk c][ntile][lane=q*16+c16][8 shorts] — wave B-fragment loads
// are 16B/lane coalesced straight from L2 (no LDS staging).
__global__ __launch_bounds__(256) void split_w_kernel(
    const float* __restrict__ W, unsigned short* __restrict__ Wf, int total)
{
    int id = blockIdx.x * 256 + threadIdx.x;
    if (id >= total) return;
    int s = id >> 15;
    int rem = id & 32767;
    int k = rem >> 7;                 // 0..255
    int nn = rem & 127;               // col
    float a = W[id];
    unsigned short hi = f2bf(a);
    float r = a - bf2f(hi);
    unsigned short mi = f2bf(r);
    int c   = k >> 5;                 // chunk
    int kin = k & 31;
    int q   = kin >> 3;
    int ko  = kin & 7;
    int nt  = nn >> 4;
    int c16 = nn & 15;
    int lane = q * 16 + c16;
    size_t base = (size_t)s * 65536 + (size_t)c * 4096 + (size_t)nt * 512
                + (size_t)lane * 8 + ko;
    Wf[base]         = hi;
    Wf[base + 32768] = mi;
}

// ---------------- Laplacian: prop[row,:] = sum_e val * hb[col,:]
// PERSISTENT: 2048 blocks; each wave-unit grid-strides over rows.
// cols are pre-scaled byte offsets. Writes single hi bf16 plane.
__global__ __launch_bounds__(256) void lap_kernel(
    const int* __restrict__ rp, const int* __restrict__ cols,
    const float* __restrict__ vals, const unsigned short* __restrict__ hb,
    unsigned short* __restrict__ ph, int n)
{
    int unit = (blockIdx.x * 256 + threadIdx.x) >> 6;    // global wave id
    int lane = threadIdx.x & 63;
    int ch2 = ((((unit & 1) << 6) + lane) << 1);         // byte offset in gather row
    int stride = (LAP_BLOCKS * 4) >> 1;                  // row stride (2 units/row)
    const char* hbase = (const char*)hb;
    for (int row = unit >> 1; row < n; row += stride) {
        int s = rp[row], e = rp[row + 1];
        float acc = 0.f;
        int t = s;
        for (; t + 8 <= e; t += 8) {
            int c0 = cols[t],     c1 = cols[t + 1], c2 = cols[t + 2], c3 = cols[t + 3];
            int c4 = cols[t + 4], c5 = cols[t + 5], c6 = cols[t + 6], c7 = cols[t + 7];
            float v0 = vals[t],     v1 = vals[t + 1], v2 = vals[t + 2], v3 = vals[t + 3];
            float v4 = vals[t + 4], v5 = vals[t + 5], v6 = vals[t + 6], v7 = vals[t + 7];
            float h0 = bf2f(*(const unsigned short*)(hbase + c0 + ch2));
            float h1 = bf2f(*(const unsigned short*)(hbase + c1 + ch2));
            float h2 = bf2f(*(const unsigned short*)(hbase + c2 + ch2));
            float h3 = bf2f(*(const unsigned short*)(hbase + c3 + ch2));
            float h4 = bf2f(*(const unsigned short*)(hbase + c4 + ch2));
            float h5 = bf2f(*(const unsigned short*)(hbase + c5 + ch2));
            float h6 = bf2f(*(const unsigned short*)(hbase + c6 + ch2));
            float h7 = bf2f(*(const unsigned short*)(hbase + c7 + ch2));
            acc += v0 * h0 + v1 * h1 + v2 * h2 + v3 * h3
                 + v4 * h4 + v5 * h5 + v6 * h6 + v7 * h7;
        }
        for (; t + 4 <= e; t += 4) {
            int c0 = cols[t], c1 = cols[t + 1], c2 = cols[t + 2], c3 = cols[t + 3];
            float v0 = vals[t], v1 = vals[t + 1], v2 = vals[t + 2], v3 = vals[t + 3];
            float h0 = bf2f(*(const unsigned short*)(hbase + c0 + ch2));
            float h1 = bf2f(*(const unsigned short*)(hbase + c1 + ch2));
            float h2 = bf2f(*(const unsigned short*)(hbase + c2 + ch2));
            float h3 = bf2f(*(const unsigned short*)(hbase + c3 + ch2));
            acc += v0 * h0 + v1 * h1 + v2 * h2 + v3 * h3;
        }
        for (; t < e; ++t)
            acc += vals[t] * bf2f(*(const unsigned short*)(hbase + cols[t] + ch2));
        ph[row * CH + (ch2 >> 1)] = f2bf(acc);
    }
}

// bias2[c] = b[c] + sum_k (acc[k]/denom) * Wb[k][c]
__global__ __launch_bounds__(256) void avg_bias_kernel(
    const float* __restrict__ acc, const float* __restrict__ denom,
    const float* __restrict__ Wb, const float* __restrict__ b,
    float* __restrict__ bias2)
{
    __shared__ float avg_s[128];
    __shared__ float partial[256];
    int tid = threadIdx.x;
    if (tid < 128) avg_s[tid] = acc[tid] / denom[0];
    __syncthreads();
    int c = tid & 127;
    int h = tid >> 7;
    float o = 0.f;
#pragma unroll 8
    for (int k = h * 64; k < h * 64 + 64; ++k) o += avg_s[k] * Wb[(size_t)k * CH + c];
    partial[tid] = o;
    __syncthreads();
    if (tid < 128) bias2[tid] = b[tid] + partial[tid] + partial[tid + 128];
}

// ---------------- MFMA GEMM: 32-row x 128-col tile, direct-L2 B frags ----------
// Grid 1563 -> ~6 blocks/CU (24 waves/CU target, 2x R14's 12 — the gemm is
// latency-bound: R15 proved bytes don't bind; R14's grid was the occupancy cap).
// R11's 32-row failure was W-staging doubling — eliminated since R14 (B frags
// come straight from fragment-ordered Wf in L2). LDS: 10.25 KB A double-buffer.
// Scattered epilogue (R14 style — 19 us faster than R15's LDS-staged one).
__global__ __launch_bounds__(256) void gemm_mfma_kernel(
    const unsigned short* __restrict__ Ah, const unsigned short* __restrict__ Al,
    const unsigned short* __restrict__ Ph,
    const unsigned short* __restrict__ Wf, const float* __restrict__ bias,
    const float* __restrict__ res, float* __restrict__ out,
    unsigned short* __restrict__ hbh, unsigned short* __restrict__ hbl,
    const float* __restrict__ mask, float* __restrict__ accp,
    int n, int nch)
{
    __shared__ unsigned short As[2][2][32][40];   // [buf][plane][row][k]
    __shared__ float csum[128];
    const int tid = threadIdx.x;
    const int m_base = blockIdx.x * 32;
    const int wid = tid >> 6;
    const int lane = tid & 63;
    const int wm = wid & 1, wn = wid >> 1;        // wave row-half (16) / col-half (64)
    const int q = lane >> 4, c16 = lane & 15;

    f32x4 acc[4];
#pragma unroll
    for (int j = 0; j < 4; j++) acc[j] = (f32x4){0.f, 0.f, 0.f, 0.f};

    // A staging: 256 threads = 2 planes x 32 rows x 4 segs of 8 shorts
    const int ap  = tid >> 7;                     // plane 0/1
    const int aw  = tid & 127;
    const int ar  = aw >> 2;                      // row 0..31
    const int acol = (aw & 3) << 3;               // k offset in shorts
    const int anode = m_base + ar;
    const bool arow_ok = (anode < n);
    const unsigned short* Abase = (ap ? Al : Ah) + (size_t)anode * CH + acol;
    const unsigned short* Pbase = Ph + (size_t)anode * CH + acol;
    const unsigned short* wf0 = Wf + (size_t)(wn * 4) * 512 + (size_t)lane * 8;
    const uint4 z4 = {0u, 0u, 0u, 0u};

    // prologue: stage dense chunk 0 into buf 0 (both planes, one store/thread)
    {
        uint4 v = arow_ok ? *(const uint4*)Abase : z4;
        *(uint4*)&As[0][ap][ar][acol] = v;
    }
    __syncthreads();

    uint4 aR;
    // ---- dense chunks 0..3: 2 A-planes, 3 MFMA per ntile ----
#pragma unroll
    for (int ch = 0; ch < 4; ++ch) {
        const int cur = ch & 1, nxt = cur ^ 1;
        if (ch < 3) {
            aR = arow_ok ? *(const uint4*)(Abase + (ch + 1) * 32) : z4;
        } else if (nch > 4) {
            aR = (ap == 0 && arow_ok) ? *(const uint4*)Pbase : z4;
        }
        s16x8 b0[4], b1[4];
        const unsigned short* wp = wf0 + (size_t)ch * 4096;
#pragma unroll
        for (int nt = 0; nt < 4; ++nt) {
            b0[nt] = *(const s16x8*)(wp + nt * 512);
            b1[nt] = *(const s16x8*)(wp + nt * 512 + 32768);
        }
        const int m = wm * 16 + c16;
        s16x8 a0 = *(const s16x8*)&As[cur][0][m][q * 8];
        s16x8 a1 = *(const s16x8*)&As[cur][1][m][q * 8];
#pragma unroll
        for (int nt = 0; nt < 4; ++nt) {
            f32x4 c = acc[nt];
            c = __builtin_amdgcn_mfma_f32_16x16x32_bf16(a0, b0[nt], c, 0, 0, 0);
            c = __builtin_amdgcn_mfma_f32_16x16x32_bf16(a0, b1[nt], c, 0, 0, 0);
            c = __builtin_amdgcn_mfma_f32_16x16x32_bf16(a1, b0[nt], c, 0, 0, 0);
            acc[nt] = c;
        }
        if (ch < 3) {
            *(uint4*)&As[nxt][ap][ar][acol] = aR;
        } else if (nch > 4) {
            if (ap == 0) *(uint4*)&As[nxt][0][ar][acol] = aR;
        }
        __syncthreads();
    }
    // ---- prop chunks 4..nch-1: 1 A-plane (ph), 2 MFMA per ntile ----
    for (int ch = 4; ch < nch; ++ch) {
        const int cur = ch & 1, nxt = cur ^ 1;
        if (ch + 1 < nch)
            aR = (ap == 0 && arow_ok) ? *(const uint4*)(Pbase + (ch - 3) * 32) : z4;
        s16x8 b0[4], b1[4];
        const unsigned short* wp = wf0 + (size_t)ch * 4096;
#pragma unroll
        for (int nt = 0; nt < 4; ++nt) {
            b0[nt] = *(const s16x8*)(wp + nt * 512);
            b1[nt] = *(const s16x8*)(wp + nt * 512 + 32768);
        }
        const int m = wm * 16 + c16;
        s16x8 a0 = *(const s16x8*)&As[cur][0][m][q * 8];
#pragma unroll
        for (int nt = 0; nt < 4; ++nt) {
            f32x4 c = acc[nt];
            c = __builtin_amdgcn_mfma_f32_16x16x32_bf16(a0, b0[nt], c, 0, 0, 0);
            c = __builtin_amdgcn_mfma_f32_16x16x32_bf16(a0, b1[nt], c, 0, 0, 0);
            acc[nt] = c;
        }
        if (ch + 1 < nch) {
            if (ap == 0) *(uint4*)&As[nxt][0][ar][acol] = aR;
        }
        __syncthreads();
    }

    // ---- epilogue: scattered (R14 style) + fused column-reduce ----
    if (accp) {
        if (tid < 128) csum[tid] = 0.f;
        __syncthreads();
    }
    float colsum[4] = {0.f, 0.f, 0.f, 0.f};
#pragma unroll
    for (int nt = 0; nt < 4; ++nt) {
        int col = wn * 64 + nt * 16 + c16;
        float bv = bias[col];
        int row0 = m_base + wm * 16 + q * 4;
#pragma unroll
        for (int r = 0; r < 4; ++r) {
            int row = row0 + r;
            if (row < n) {
                float o = acc[nt][r] + bv;
                size_t idx = (size_t)row * CH + col;
                if (res) o += res[idx];
                if (out) out[idx] = o;
                float e = eluf(o);
                unsigned short hi = f2bf(e);
                hbh[idx] = hi;
                hbl[idx] = f2bf(e - bf2f(hi));
                if (accp) colsum[nt] += mask[row] * e;
            }
        }
    }
    if (accp) {
#pragma unroll
        for (int nt = 0; nt < 4; ++nt)
            atomicAdd(&csum[wn * 64 + nt * 16 + c16], colsum[nt]);
        __syncthreads();
        if (tid < 128) atomicAdd(&accp[tid], csum[tid]);
    }
}

// ---------------- final head: out[n] = elu(x) @ W2 + b2 + inputs[n,0]; persistent ----------------
__global__ __launch_bounds__(256) void final_kernel(
    const unsigned short* __restrict__ hh, const unsigned short* __restrict__ hl,
    const float* __restrict__ W2, const float* __restrict__ b2,
    const float* __restrict__ in, float* __restrict__ out, int n)
{
    int wave = (blockIdx.x * blockDim.x + threadIdx.x) >> 6;
    int lane = threadIdx.x & 63;
    int stride = gridDim.x * 4;
    for (int row = wave; row < n; row += stride) {
        size_t i1 = (size_t)row * CH + lane;
        size_t i2 = i1 + 64;
        float v = (bf2f(hh[i1]) + bf2f(hl[i1])) * W2[lane]
                + (bf2f(hh[i2]) + bf2f(hl[i2])) * W2[64 + lane];
#pragma unroll
        for (int off = 32; off > 0; off >>= 1) v += __shfl_down(v, off, 64);
        if (lane == 0) out[row] = v + b2[0] + in[(size_t)row * 3];
    }
}

extern "C" void kernel_launch(void* const* d_in, const int* in_sizes, int n_in,
                              void* d_out, int out_size, void* d_ws, size_t ws_size,
                              hipStream_t stream)
{
    const int*   L_row   = (const int*)d_in[0];
    const int*   L_col   = (const int*)d_in[1];
    const float* L_val   = (const float*)d_in[2];
    const float* mask    = (const float*)d_in[3];
    const float* inputs  = (const float*)d_in[4];
    const float* conv1_W = (const float*)d_in[5];
    const float* conv1_b = (const float*)d_in[6];
    const float* blocks_W = (const float*)d_in[7];
    const float* blocks_b = (const float*)d_in[8];
    const float* conv2_W = (const float*)d_in[9];
    const float* conv2_b = (const float*)d_in[10];
    float* out = (float*)d_out;

    const int N = N_NODES, E = N_EDGES;
    const size_t NF = (size_t)N * CH;
    const int NPAD = 50048;
    const int NB = (N + 1023) / 1024;

    float* ws = (float*)d_ws;
    float* x0 = ws;                                   // fp32 residual chain (2 slots)
    float* x1 = x0 + NF;
    unsigned short* hbh0 = (unsigned short*)(x1 + NF);  // elu planes, slot 0
    unsigned short* hbl0 = hbh0 + NF;
    unsigned short* hbh1 = hbl0 + NF;                   // elu planes, slot 1
    unsigned short* hbl1 = hbh1 + NF;
    unsigned short* ph   = hbl1 + NF;                   // prop hi plane
    int* cnt     = (int*)(ph + 2 * NF);                 // (gap keeps prior layout size)
    int* cursor  = cnt + NPAD;
    int* row_ptr = cursor + NPAD;
    int* bsum    = row_ptr + NPAD;
    int* boff    = bsum + 64;
    int* col_s   = boff + 64;
    float* val_s = (float*)(col_s + E);
    float* acc_base = val_s + E;                        // 14 slots x 128
    float* denom    = acc_base + 14 * CH;
    float* bias2    = denom + 16;
    unsigned short* wt = (unsigned short*)(bias2 + 128 + 32);  // 30*65536 shorts (frag order)

    zero_int_kernel<<<(2 * NPAD + 255) / 256, 256, 0, stream>>>(cnt, 2 * NPAD);
    zero_float_kernel<<<(14 * CH + 16 + 255) / 256, 256, 0, stream>>>(acc_base, 14 * CH + 16);
    count_kernel<<<(E + 255) / 256, 256, 0, stream>>>(L_row, cnt, E);
    block_reduce_kernel<<<NB, 1024, 0, stream>>>(cnt, bsum, N);
    scan_small_kernel<<<1, 64, 0, stream>>>(bsum, boff, NB);
    block_scan_kernel<<<NB, 1024, 0, stream>>>(cnt, boff, row_ptr, N);
    fill_kernel<<<(E + 255) / 256, 256, 0, stream>>>(L_row, L_col, L_val, cursor,
                                                     row_ptr, col_s, val_s, E);
    mask_sum_kernel<<<64, 256, 0, stream>>>(mask, denom, N);
    split_w_kernel<<<(30 * 32768 + 255) / 256, 256, 0, stream>>>(blocks_W, wt, 30 * 32768);

    conv1_kernel<<<(N * CH + 255) / 256, 256, 0, stream>>>(inputs, conv1_W, conv1_b,
                                                           x0, hbh0, hbl0, N);

    float* xin = x0;
    float* xout = x1;
    const int gemm_grid = (N + 31) / 32;        // 1563 blocks, 32-row tiles

    for (int i = 0; i < N_LAYERS; ++i) {
        for (int j = 0; j < 2; ++j) {
            int s = i * 2 + j;
            const unsigned short* Wt_s = wt + (size_t)s * 65536;
            const float* b = blocks_b + (size_t)s * CH;
            const unsigned short* ah = (j == 0) ? hbh0 : hbh1;
            const unsigned short* al = (j == 0) ? hbl0 : hbl1;
            unsigned short* oh = (j == 0) ? hbh1 : hbh0;
            unsigned short* ol = (j == 0) ? hbl1 : hbl0;
            const float* resp = (j == 1) ? xin : nullptr;
            float* outp = (j == 1) ? xout : nullptr;
            // fused column-reduce slot: gemm (even i, j=1) feeds avg step (i+1, 0);
            // gemm (odd i, j=0) feeds avg step (i, 1). Slot index = producing layer i.
            float* accp = nullptr;
            if (j == 1 && (i % 2 == 0) && i < 14) accp = acc_base + (size_t)i * CH;
            if (j == 0 && (i % 2 == 1))           accp = acc_base + (size_t)i * CH;
            if (i % 2 == 0) {
                lap_kernel<<<LAP_BLOCKS, 256, 0, stream>>>(row_ptr, col_s, val_s, ah, ph, N);
                gemm_mfma_kernel<<<gemm_grid, 256, 0, stream>>>(ah, al, ph, Wt_s, b,
                                                                resp, outp, oh, ol,
                                                                mask, accp, N, 8);
            } else {
                // acc slot for this avg step: (i-1)+j  (filled by the producing gemm)
                float* acc = acc_base + (size_t)(i - 1 + j) * CH;
                avg_bias_kernel<<<1, 256, 0, stream>>>(acc, denom,
                    blocks_W + (size_t)s * 256 * CH + 128 * CH, b, bias2);
                gemm_mfma_kernel<<<gemm_grid, 256, 0, stream>>>(ah, al, nullptr, Wt_s,
                                                                bias2, resp, outp, oh, ol,
                                                                mask, accp, N, 4);
            }
        }
        float* t = xin; xin = xout; xout = t;
    }
    // after each layer the elu planes of the layer output land back in slot 0
    final_kernel<<<LAP_BLOCKS, 256, 0, stream>>>(hbh0, hbl0, conv2_W, conv2_b, inputs, out, N);
}

// Round 17
// 1915.191 us; speedup vs baseline: 1.2354x; 1.2354x over previous
//
#include <hip/hip_runtime.h>
#include <hip/hip_bf16.h>

#define N_NODES 50000
#define N_EDGES 600000
#define CH 128
#define N_LAYERS 15
#define LAP_BLOCKS 2048

typedef float f32x4 __attribute__((ext_vector_type(4)));
typedef short s16x8 __attribute__((ext_vector_type(8)));

__device__ __forceinline__ float eluf(float v) {
    return v > 0.f ? v : (__expf(v) - 1.f);
}

// float -> bf16 round-to-nearest-even, raw ushort
__device__ __forceinline__ unsigned short f2bf(float f) {
    unsigned int u = __float_as_uint(f);
    unsigned int r = (u + 0x7FFFu + ((u >> 16) & 1u)) >> 16;
    return (unsigned short)r;
}
__device__ __forceinline__ float bf2f(unsigned short h) {
    return __uint_as_float(((unsigned int)h) << 16);
}

// ---------------- conv1: [N,3] @ [3,128] + b ; writes x fp32 + elu planes ----------------
__global__ __launch_bounds__(256) void conv1_kernel(
    const float* __restrict__ in, const float* __restrict__ W1,
    const float* __restrict__ b1, float* __restrict__ x,
    unsigned short* __restrict__ hbh, unsigned short* __restrict__ hbl, int n)
{
    int idx = blockIdx.x * blockDim.x + threadIdx.x;
    if (idx >= n * CH) return;
    int node = idx >> 7;
    int c = idx & 127;
    float o = b1[c]
            + in[(size_t)node * 3 + 0] * W1[0 * CH + c]
            + in[(size_t)node * 3 + 1] * W1[1 * CH + c]
            + in[(size_t)node * 3 + 2] * W1[2 * CH + c];
    x[idx] = o;
    float e = eluf(o);
    unsigned short hi = f2bf(e);
    hbh[idx] = hi;
    hbl[idx] = f2bf(e - bf2f(hi));
}

// ---------------- zero helpers ----------------
__global__ __launch_bounds__(256) void zero_int_kernel(int* __restrict__ p, int n) {
    int i = blockIdx.x * blockDim.x + threadIdx.x;
    if (i < n) p[i] = 0;
}
__global__ __launch_bounds__(256) void zero_float_kernel(float* __restrict__ p, int n) {
    int i = blockIdx.x * blockDim.x + threadIdx.x;
    if (i < n) p[i] = 0.f;
}

// ---------------- CSR build ----------------
__global__ __launch_bounds__(256) void count_kernel(
    const int* __restrict__ row, int* __restrict__ cnt, int e)
{
    int i = blockIdx.x * blockDim.x + threadIdx.x;
    if (i < e) atomicAdd(&cnt[row[i]], 1);
}

__global__ __launch_bounds__(1024) void block_reduce_kernel(
    const int* __restrict__ cnt, int* __restrict__ bsum, int n)
{
    __shared__ int sd[1024];
    int tid = threadIdx.x;
    int i = blockIdx.x * 1024 + tid;
    sd[tid] = (i < n) ? cnt[i] : 0;
    __syncthreads();
    for (int off = 512; off > 0; off >>= 1) {
        if (tid < off) sd[tid] += sd[tid + off];
        __syncthreads();
    }
    if (tid == 0) bsum[blockIdx.x] = sd[0];
}

__global__ __launch_bounds__(64) void scan_small_kernel(
    const int* __restrict__ bsum, int* __restrict__ boff, int nb)
{
    int lane = threadIdx.x;
    int orig = (lane < nb) ? bsum[lane] : 0;
    int v = orig;
#pragma unroll
    for (int d = 1; d < 64; d <<= 1) {
        int t = __shfl_up(v, d, 64);
        if (lane >= d) v += t;
    }
    if (lane < nb) boff[lane] = v - orig;  // exclusive
}

__global__ __launch_bounds__(1024) void block_scan_kernel(
    const int* __restrict__ cnt, const int* __restrict__ boff,
    int* __restrict__ row_ptr, int n)
{
    __shared__ int sd[1024];
    int tid = threadIdx.x;
    int i = blockIdx.x * 1024 + tid;
    sd[tid] = (i < n) ? cnt[i] : 0;
    __syncthreads();
    for (int off = 1; off < 1024; off <<= 1) {
        int t = (tid >= off) ? sd[tid - off] : 0;
        __syncthreads();
        sd[tid] += t;
        __syncthreads();
    }
    if (i < n) row_ptr[i + 1] = sd[tid] + boff[blockIdx.x];
    if (i == 0) row_ptr[0] = 0;
}

// col_s stores byte offset of the gather row start: col * CH * 2 = col << 8
__global__ __launch_bounds__(256) void fill_kernel(
    const int* __restrict__ row, const int* __restrict__ col,
    const float* __restrict__ val, int* __restrict__ cursor,
    const int* __restrict__ row_ptr, int* __restrict__ col_s,
    float* __restrict__ val_s, int e)
{
    int i = blockIdx.x * blockDim.x + threadIdx.x;
    if (i >= e) return;
    int r = row[i];
    int pos = atomicAdd(&cursor[r], 1);
    int dst = row_ptr[r] + pos;
    col_s[dst] = col[i] << 8;
    val_s[dst] = val[i];
}

// ---------------- mask denominator (once per call) ----------------
__global__ __launch_bounds__(256) void mask_sum_kernel(
    const float* __restrict__ mask, float* __restrict__ denom, int n)
{
    __shared__ float sd[256];
    int tid = threadIdx.x;
    float s = 0.f;
    for (int i = blockIdx.x * 256 + tid; i < n; i += gridDim.x * 256) s += mask[i];
    sd[tid] = s;
    __syncthreads();
    for (int off = 128; off > 0; off >>= 1) {
        if (tid < off) sd[tid] += sd[tid + off];
        __syncthreads();
    }
    if (tid == 0) atomicAdd(denom, sd[0]);
}

// ---- W pre-split into MFMA-FRAGMENT-ordered layout:
// Wf[s][plane][chunk c][ntile][lane=q*16+c16][8 shorts] — wave B-fragment loads
// are 16B/lane coalesced straight from L2 (no LDS staging).
__global__ __launch_bounds__(256) void split_w_kernel(
    const float* __restrict__ W, unsigned short* __restrict__ Wf, int total)
{
    int id = blockIdx.x * 256 + threadIdx.x;
    if (id >= total) return;
    int s = id >> 15;
    int rem = id & 32767;
    int k = rem >> 7;                 // 0..255
    int nn = rem & 127;               // col
    float a = W[id];
    unsigned short hi = f2bf(a);
    float r = a - bf2f(hi);
    unsigned short mi = f2bf(r);
    int c   = k >> 5;                 // chunk
    int kin = k & 31;
    int q   = kin >> 3;
    int ko  = kin & 7;
    int nt  = nn >> 4;
    int c16 = nn & 15;
    int lane = q * 16 + c16;
    size_t base = (size_t)s * 65536 + (size_t)c * 4096 + (size_t)nt * 512
                + (size_t)lane * 8 + ko;
    Wf[base]         = hi;
    Wf[base + 32768] = mi;
}

// ---------------- Laplacian: prop[row,:] = sum_e val * hb[col,:]
// PERSISTENT: 2048 blocks; each wave-unit grid-strides over rows.
// cols are pre-scaled byte offsets. Writes single hi bf16 plane.
__global__ __launch_bounds__(256) void lap_kernel(
    const int* __restrict__ rp, const int* __restrict__ cols,
    const float* __restrict__ vals, const unsigned short* __restrict__ hb,
    unsigned short* __restrict__ ph, int n)
{
    int unit = (blockIdx.x * 256 + threadIdx.x) >> 6;    // global wave id
    int lane = threadIdx.x & 63;
    int ch2 = ((((unit & 1) << 6) + lane) << 1);         // byte offset in gather row
    int stride = (LAP_BLOCKS * 4) >> 1;                  // row stride (2 units/row)
    const char* hbase = (const char*)hb;
    for (int row = unit >> 1; row < n; row += stride) {
        int s = rp[row], e = rp[row + 1];
        float acc = 0.f;
        int t = s;
        for (; t + 8 <= e; t += 8) {
            int c0 = cols[t],     c1 = cols[t + 1], c2 = cols[t + 2], c3 = cols[t + 3];
            int c4 = cols[t + 4], c5 = cols[t + 5], c6 = cols[t + 6], c7 = cols[t + 7];
            float v0 = vals[t],     v1 = vals[t + 1], v2 = vals[t + 2], v3 = vals[t + 3];
            float v4 = vals[t + 4], v5 = vals[t + 5], v6 = vals[t + 6], v7 = vals[t + 7];
            float h0 = bf2f(*(const unsigned short*)(hbase + c0 + ch2));
            float h1 = bf2f(*(const unsigned short*)(hbase + c1 + ch2));
            float h2 = bf2f(*(const unsigned short*)(hbase + c2 + ch2));
            float h3 = bf2f(*(const unsigned short*)(hbase + c3 + ch2));
            float h4 = bf2f(*(const unsigned short*)(hbase + c4 + ch2));
            float h5 = bf2f(*(const unsigned short*)(hbase + c5 + ch2));
            float h6 = bf2f(*(const unsigned short*)(hbase + c6 + ch2));
            float h7 = bf2f(*(const unsigned short*)(hbase + c7 + ch2));
            acc += v0 * h0 + v1 * h1 + v2 * h2 + v3 * h3
                 + v4 * h4 + v5 * h5 + v6 * h6 + v7 * h7;
        }
        for (; t + 4 <= e; t += 4) {
            int c0 = cols[t], c1 = cols[t + 1], c2 = cols[t + 2], c3 = cols[t + 3];
            float v0 = vals[t], v1 = vals[t + 1], v2 = vals[t + 2], v3 = vals[t + 3];
            float h0 = bf2f(*(const unsigned short*)(hbase + c0 + ch2));
            float h1 = bf2f(*(const unsigned short*)(hbase + c1 + ch2));
            float h2 = bf2f(*(const unsigned short*)(hbase + c2 + ch2));
            float h3 = bf2f(*(const unsigned short*)(hbase + c3 + ch2));
            acc += v0 * h0 + v1 * h1 + v2 * h2 + v3 * h3;
        }
        for (; t < e; ++t)
            acc += vals[t] * bf2f(*(const unsigned short*)(hbase + cols[t] + ch2));
        ph[row * CH + (ch2 >> 1)] = f2bf(acc);
    }
}

// ---------------- MFMA GEMM: R14 structure (64-row tile, direct-L2 B frags,
// A-only LDS double-buffer, scattered epilogue) + in-kernel bias2 computation
// for avg steps (replaces the 14 serialized single-block avg_bias dispatches).
__global__ __launch_bounds__(256) void gemm_mfma_kernel(
    const unsigned short* __restrict__ Ah, const unsigned short* __restrict__ Al,
    const unsigned short* __restrict__ Ph,
    const unsigned short* __restrict__ Wf, const float* __restrict__ bias,
    const float* __restrict__ res, float* __restrict__ out,
    unsigned short* __restrict__ hbh, unsigned short* __restrict__ hbl,
    const float* __restrict__ mask, float* __restrict__ accp,
    const float* __restrict__ accv, const float* __restrict__ denom,
    const float* __restrict__ Wb,
    int n, int nch)
{
    __shared__ unsigned short As[2][2][64][40];   // [buf][plane][row][k]
    __shared__ float csum[128];
    __shared__ float avg_s[128];
    __shared__ float partial[256];
    __shared__ float bias_s[128];
    const int tid = threadIdx.x;
    const int m_base = blockIdx.x * 64;
    const int wid = tid >> 6;
    const int lane = tid & 63;
    const int wm = wid & 1, wn = wid >> 1;        // wave row-half / col-half
    const int q = lane >> 4, c16 = lane & 15;

    f32x4 acc[2][4];
#pragma unroll
    for (int i = 0; i < 2; i++)
#pragma unroll
        for (int j = 0; j < 4; j++) acc[i][j] = (f32x4){0.f, 0.f, 0.f, 0.f};

    const int ar = tid >> 2;                      // A row 0..63
    const int acol = (tid & 3) << 3;              // k offset in shorts
    const int anode = m_base + ar;
    const bool arow_ok = (anode < n);
    const unsigned short* Abase_h = Ah + (size_t)anode * CH + acol;
    const unsigned short* Abase_l = Al + (size_t)anode * CH + acol;
    const unsigned short* Pbase   = Ph + (size_t)anode * CH + acol;
    const unsigned short* wf0 = Wf + (size_t)(wn * 4) * 512 + (size_t)lane * 8;
    const uint4 z4 = {0u, 0u, 0u, 0u};

    // bias_s / avg_s init (overlaps with the A prologue below)
    if (tid < 128) {
        bias_s[tid] = bias[tid];
        if (accv) avg_s[tid] = accv[tid] / denom[0];
    }
    // prologue: stage dense chunk 0 into buf 0
    {
        uint4 v  = arow_ok ? *(const uint4*)Abase_h : z4;
        uint4 v2 = arow_ok ? *(const uint4*)Abase_l : z4;
        *(uint4*)&As[0][0][ar][acol] = v;
        *(uint4*)&As[0][1][ar][acol] = v2;
    }
    __syncthreads();
    // in-kernel bias2: bias_s += (acc/denom) @ Wb  (avg steps only; block-uniform)
    if (accv) {
        int c = tid & 127;
        int h = tid >> 7;
        float o = 0.f;
#pragma unroll 8
        for (int k = h * 64; k < h * 64 + 64; ++k) o += avg_s[k] * Wb[(size_t)k * CH + c];
        partial[tid] = o;
        __syncthreads();
        if (tid < 128) bias_s[tid] += partial[tid] + partial[tid + 128];
        // visibility to epilogue guaranteed by the K-loop barriers below
    }

    uint4 aR0, aR1;
    // ---- dense chunks 0..3 ----
#pragma unroll
    for (int ch = 0; ch < 4; ++ch) {
        const int cur = ch & 1, nxt = cur ^ 1;
        if (ch < 3) {
            aR0 = arow_ok ? *(const uint4*)(Abase_h + (ch + 1) * 32) : z4;
            aR1 = arow_ok ? *(const uint4*)(Abase_l + (ch + 1) * 32) : z4;
        } else if (nch > 4) {
            aR0 = arow_ok ? *(const uint4*)Pbase : z4;
        }
        s16x8 b0[4], b1[4];
        const unsigned short* wp = wf0 + (size_t)ch * 4096;
#pragma unroll
        for (int nt = 0; nt < 4; ++nt) {
            b0[nt] = *(const s16x8*)(wp + nt * 512);
            b1[nt] = *(const s16x8*)(wp + nt * 512 + 32768);
        }
        s16x8 a0[2], a1[2];
#pragma unroll
        for (int mt = 0; mt < 2; ++mt) {
            int m = wm * 32 + mt * 16 + c16;
            a0[mt] = *(const s16x8*)&As[cur][0][m][q * 8];
            a1[mt] = *(const s16x8*)&As[cur][1][m][q * 8];
        }
#pragma unroll
        for (int mt = 0; mt < 2; ++mt)
#pragma unroll
            for (int nt = 0; nt < 4; ++nt) {
                f32x4 c = acc[mt][nt];
                c = __builtin_amdgcn_mfma_f32_16x16x32_bf16(a0[mt], b0[nt], c, 0, 0, 0);
                c = __builtin_amdgcn_mfma_f32_16x16x32_bf16(a0[mt], b1[nt], c, 0, 0, 0);
                c = __builtin_amdgcn_mfma_f32_16x16x32_bf16(a1[mt], b0[nt], c, 0, 0, 0);
                acc[mt][nt] = c;
            }
        if (ch < 3) {
            *(uint4*)&As[nxt][0][ar][acol] = aR0;
            *(uint4*)&As[nxt][1][ar][acol] = aR1;
        } else if (nch > 4) {
            *(uint4*)&As[nxt][0][ar][acol] = aR0;
        }
        __syncthreads();
    }
    // ---- prop chunks 4..nch-1: 1 A-plane, 2 MFMA ----
    for (int ch = 4; ch < nch; ++ch) {
        const int cur = ch & 1, nxt = cur ^ 1;
        if (ch + 1 < nch)
            aR0 = arow_ok ? *(const uint4*)(Pbase + (ch - 3) * 32) : z4;
        s16x8 b0[4], b1[4];
        const unsigned short* wp = wf0 + (size_t)ch * 4096;
#pragma unroll
        for (int nt = 0; nt < 4; ++nt) {
            b0[nt] = *(const s16x8*)(wp + nt * 512);
            b1[nt] = *(const s16x8*)(wp + nt * 512 + 32768);
        }
        s16x8 a0[2];
#pragma unroll
        for (int mt = 0; mt < 2; ++mt) {
            int m = wm * 32 + mt * 16 + c16;
            a0[mt] = *(const s16x8*)&As[cur][0][m][q * 8];
        }
#pragma unroll
        for (int mt = 0; mt < 2; ++mt)
#pragma unroll
            for (int nt = 0; nt < 4; ++nt) {
                f32x4 c = acc[mt][nt];
                c = __builtin_amdgcn_mfma_f32_16x16x32_bf16(a0[mt], b0[nt], c, 0, 0, 0);
                c = __builtin_amdgcn_mfma_f32_16x16x32_bf16(a0[mt], b1[nt], c, 0, 0, 0);
                acc[mt][nt] = c;
            }
        if (ch + 1 < nch)
            *(uint4*)&As[nxt][0][ar][acol] = aR0;
        __syncthreads();
    }

    // ---- epilogue: scattered (R14 style) + fused column-reduce ----
    if (accp) {
        if (tid < 128) csum[tid] = 0.f;
        __syncthreads();
    }
    float colsum[4] = {0.f, 0.f, 0.f, 0.f};
#pragma unroll
    for (int mt = 0; mt < 2; ++mt) {
#pragma unroll
        for (int nt = 0; nt < 4; ++nt) {
            int col = wn * 64 + nt * 16 + c16;
            float bv = bias_s[col];
            int row0 = m_base + wm * 32 + mt * 16 + q * 4;
#pragma unroll
            for (int r = 0; r < 4; ++r) {
                int row = row0 + r;
                if (row < n) {
                    float o = acc[mt][nt][r] + bv;
                    size_t idx = (size_t)row * CH + col;
                    if (res) o += res[idx];
                    if (out) out[idx] = o;
                    float e = eluf(o);
                    unsigned short hi = f2bf(e);
                    hbh[idx] = hi;
                    hbl[idx] = f2bf(e - bf2f(hi));
                    if (accp) colsum[nt] += mask[row] * e;
                }
            }
        }
    }
    if (accp) {
#pragma unroll
        for (int nt = 0; nt < 4; ++nt)
            atomicAdd(&csum[wn * 64 + nt * 16 + c16], colsum[nt]);
        __syncthreads();
        if (tid < 128) atomicAdd(&accp[tid], csum[tid]);
    }
}

// ---------------- final head: out[n] = elu(x) @ W2 + b2 + inputs[n,0]; persistent ----------------
__global__ __launch_bounds__(256) void final_kernel(
    const unsigned short* __restrict__ hh, const unsigned short* __restrict__ hl,
    const float* __restrict__ W2, const float* __restrict__ b2,
    const float* __restrict__ in, float* __restrict__ out, int n)
{
    int wave = (blockIdx.x * blockDim.x + threadIdx.x) >> 6;
    int lane = threadIdx.x & 63;
    int stride = gridDim.x * 4;
    for (int row = wave; row < n; row += stride) {
        size_t i1 = (size_t)row * CH + lane;
        size_t i2 = i1 + 64;
        float v = (bf2f(hh[i1]) + bf2f(hl[i1])) * W2[lane]
                + (bf2f(hh[i2]) + bf2f(hl[i2])) * W2[64 + lane];
#pragma unroll
        for (int off = 32; off > 0; off >>= 1) v += __shfl_down(v, off, 64);
        if (lane == 0) out[row] = v + b2[0] + in[(size_t)row * 3];
    }
}

extern "C" void kernel_launch(void* const* d_in, const int* in_sizes, int n_in,
                              void* d_out, int out_size, void* d_ws, size_t ws_size,
                              hipStream_t stream)
{
    const int*   L_row   = (const int*)d_in[0];
    const int*   L_col   = (const int*)d_in[1];
    const float* L_val   = (const float*)d_in[2];
    const float* mask    = (const float*)d_in[3];
    const float* inputs  = (const float*)d_in[4];
    const float* conv1_W = (const float*)d_in[5];
    const float* conv1_b = (const float*)d_in[6];
    const float* blocks_W = (const float*)d_in[7];
    const float* blocks_b = (const float*)d_in[8];
    const float* conv2_W = (const float*)d_in[9];
    const float* conv2_b = (const float*)d_in[10];
    float* out = (float*)d_out;

    const int N = N_NODES, E = N_EDGES;
    const size_t NF = (size_t)N * CH;
    const int NPAD = 50048;
    const int NB = (N + 1023) / 1024;

    float* ws = (float*)d_ws;
    float* x0 = ws;                                   // fp32 residual chain (2 slots)
    float* x1 = x0 + NF;
    unsigned short* hbh0 = (unsigned short*)(x1 + NF);  // elu planes, slot 0
    unsigned short* hbl0 = hbh0 + NF;
    unsigned short* hbh1 = hbl0 + NF;                   // elu planes, slot 1
    unsigned short* hbl1 = hbh1 + NF;
    unsigned short* ph   = hbl1 + NF;                   // prop hi plane
    int* cnt     = (int*)(ph + 2 * NF);                 // (gap keeps prior layout size)
    int* cursor  = cnt + NPAD;
    int* row_ptr = cursor + NPAD;
    int* bsum    = row_ptr + NPAD;
    int* boff    = bsum + 64;
    int* col_s   = boff + 64;
    float* val_s = (float*)(col_s + E);
    float* acc_base = val_s + E;                        // 14 slots x 128
    float* denom    = acc_base + 14 * CH;
    unsigned short* wt = (unsigned short*)(denom + 16 + 160);  // 30*65536 shorts (frag order)

    zero_int_kernel<<<(2 * NPAD + 255) / 256, 256, 0, stream>>>(cnt, 2 * NPAD);
    zero_float_kernel<<<(14 * CH + 16 + 255) / 256, 256, 0, stream>>>(acc_base, 14 * CH + 16);
    count_kernel<<<(E + 255) / 256, 256, 0, stream>>>(L_row, cnt, E);
    block_reduce_kernel<<<NB, 1024, 0, stream>>>(cnt, bsum, N);
    scan_small_kernel<<<1, 64, 0, stream>>>(bsum, boff, NB);
    block_scan_kernel<<<NB, 1024, 0, stream>>>(cnt, boff, row_ptr, N);
    fill_kernel<<<(E + 255) / 256, 256, 0, stream>>>(L_row, L_col, L_val, cursor,
                                                     row_ptr, col_s, val_s, E);
    mask_sum_kernel<<<64, 256, 0, stream>>>(mask, denom, N);
    split_w_kernel<<<(30 * 32768 + 255) / 256, 256, 0, stream>>>(blocks_W, wt, 30 * 32768);

    conv1_kernel<<<(N * CH + 255) / 256, 256, 0, stream>>>(inputs, conv1_W, conv1_b,
                                                           x0, hbh0, hbl0, N);

    float* xin = x0;
    float* xout = x1;
    const int gemm_grid = (N + 63) / 64;        // 782 blocks, 64-row tiles

    for (int i = 0; i < N_LAYERS; ++i) {
        for (int j = 0; j < 2; ++j) {
            int s = i * 2 + j;
            const unsigned short* Wt_s = wt + (size_t)s * 65536;
            const float* b = blocks_b + (size_t)s * CH;
            const unsigned short* ah = (j == 0) ? hbh0 : hbh1;
            const unsigned short* al = (j == 0) ? hbl0 : hbl1;
            unsigned short* oh = (j == 0) ? hbh1 : hbh0;
            unsigned short* ol = (j == 0) ? hbl1 : hbl0;
            const float* resp = (j == 1) ? xin : nullptr;
            float* outp = (j == 1) ? xout : nullptr;
            // fused column-reduce slot: gemm (even i, j=1) feeds avg step (i+1, 0);
            // gemm (odd i, j=0) feeds avg step (i, 1). Slot index = producing layer i.
            float* accp = nullptr;
            if (j == 1 && (i % 2 == 0) && i < 14) accp = acc_base + (size_t)i * CH;
            if (j == 0 && (i % 2 == 1))           accp = acc_base + (size_t)i * CH;
            if (i % 2 == 0) {
                lap_kernel<<<LAP_BLOCKS, 256, 0, stream>>>(row_ptr, col_s, val_s, ah, ph, N);
                gemm_mfma_kernel<<<gemm_grid, 256, 0, stream>>>(ah, al, ph, Wt_s, b,
                                                                resp, outp, oh, ol,
                                                                mask, accp,
                                                                nullptr, denom, nullptr,
                                                                N, 8);
            } else {
                // avg step: bias2 computed inside the gemm from acc slot (i-1+j)
                const float* accv = acc_base + (size_t)(i - 1 + j) * CH;
                const float* Wb = blocks_W + (size_t)s * 256 * CH + 128 * CH;
                gemm_mfma_kernel<<<gemm_grid, 256, 0, stream>>>(ah, al, nullptr, Wt_s, b,
                                                                resp, outp, oh, ol,
                                                                mask, accp,
                                                                accv, denom, Wb,
                                                                N, 4);
            }
        }
        float* t = xin; xin = xout; xout = t;
    }
    // after each layer the elu planes of the layer output land back in slot 0
    final_kernel<<<LAP_BLOCKS, 256, 0, stream>>>(hbh0, hbl0, conv2_W, conv2_b, inputs, out, N);
}